// Round 4
// baseline (2018.710 us; speedup 1.0000x reference)
//
#include <hip/hip_runtime.h>

#define N_ROWS 65536
#define K_CODES 8192
#define DIM 256
#define CAP 48

// d_out layout (floats): [quantized_st 65536*256][loss 1][indices 65536]
#define LOSS_OFF (N_ROWS * DIM)
#define IDX_OFF (LOSS_OFF + 1)
// scratch inside d_out's quantized region (consumed before gather overwrites):
#define OUT_WBF_U16 0              // W_bf: 8192*256 u16  (4 MB)
#define OUT_ZBF_U16 2097152        // z_bf: 65536*256 u16 (32 MB)
#define OUT_CAND_F 9437184         // cand: 65536*48 uint2 (25.2 MB); ends 15728640 < 16777216

// d_ws layout (4-byte units), ~1.3 MB total
#define WS_LOSS 0
#define WS_ZNORM 64
#define WS_WNORM (WS_ZNORM + N_ROWS)
#define WS_MARGIN (WS_WNORM + K_CODES)
#define WS_ROWMAX (WS_MARGIN + N_ROWS)  // uint keys (final, written once by fused gemm)
#define WS_CNT (WS_ROWMAX + N_ROWS)     // uint
#define WS_OVF (WS_CNT + N_ROWS)        // uint counter
#define WS_OVFLIST (WS_OVF + 1)         // uint, up to N_ROWS

typedef __bf16 bf16x8 __attribute__((ext_vector_type(8)));
typedef float f32x4 __attribute__((ext_vector_type(4)));

// ---------- numerics helpers ----------

__device__ __forceinline__ float mul_rn_nofma(float a, float b) {
  float r;
  asm("v_mul_f32 %0, %1, %2" : "=v"(r) : "v"(a), "v"(b));
  return r;
}

// fp32 -> bf16 bits, RNE (error <= 2^-8 rel; the margin derivation assumes this).
__device__ __forceinline__ unsigned int f2bf(float f) {
  unsigned int u = __float_as_uint(f);
  return (u + 0x7FFFu + ((u >> 16) & 1u)) >> 16;
}

// Order-preserving float<->uint key (monotone; key 0 == -inf side).
__device__ __forceinline__ unsigned int f2key(float f) {
  unsigned int u = __float_as_uint(f);
  return (u & 0x80000000u) ? ~u : (u | 0x80000000u);
}
__device__ __forceinline__ float key2f(unsigned int k) {
  return __uint_as_float((k & 0x80000000u) ? (k ^ 0x80000000u) : ~k);
}

// Exact np matmul replica: single ascending-d fmaf chain (bit-proven rounds 1-3).
__device__ float dot_chain(const float* __restrict__ zp, const float* __restrict__ wp) {
  float acc = 0.0f;
#pragma unroll 8
  for (int d4 = 0; d4 < 64; ++d4) {
    const float4 a = *(const float4*)(zp + d4 * 4);
    const float4 b = *(const float4*)(wp + d4 * 4);
    acc = fmaf(a.x, b.x, acc);
    acc = fmaf(a.y, b.y, acc);
    acc = fmaf(a.z, b.z, acc);
    acc = fmaf(a.w, b.w, acc);
  }
  return acc;
}

// global -> LDS 16B DMA (wave-uniform LDS base + lane*16).
__device__ __forceinline__ void glds16(const void* g, void* l) {
  __builtin_amdgcn_global_load_lds(
      (const __attribute__((address_space(1))) void*)(unsigned long long)(size_t)g,
      (__attribute__((address_space(3))) void*)(unsigned int)(size_t)l, 16, 0, 0);
}

// ---------- kernels ----------

// Convert W then z to bf16 into the out-region scratch. One float4 per thread.
__global__ void precvt_kernel(const float* __restrict__ z, const float* __restrict__ W,
                              unsigned short* __restrict__ outu) {
  const int t = blockIdx.x * blockDim.x + threadIdx.x;  // 0 .. 4718591
  const int WQ = (K_CODES * DIM) / 4;                   // 524288
  const float4 v = (t < WQ) ? ((const float4*)W)[t] : ((const float4*)z)[t - WQ];
  uint2 p;
  p.x = f2bf(v.x) | (f2bf(v.y) << 16);
  p.y = f2bf(v.z) | (f2bf(v.w) << 16);
  ((uint2*)outu)[t] = p;
}

// Coalesced norms: wave handles 4 rows; 16 lanes/row replicate numpy's pairwise
// tree exactly (8 stride-8 accumulators per 128-block, fixed combine order).
__global__ void norms_kernel(const float* __restrict__ z, const float* __restrict__ W,
                             float* __restrict__ ws) {
  const int tid = threadIdx.x;
  const int l = tid & 63, w = tid >> 6;
  const int j = l & 7, b = (l >> 3) & 1, rw = l >> 4;
  const int row = blockIdx.x * 16 + w * 4 + rw;  // 0 .. 73727
  const float* src = (row < N_ROWS) ? (z + (size_t)row * DIM + b * 128)
                                    : (W + (size_t)(row - N_ROWS) * DIM + b * 128);
  float a0 = src[j];
  float r = mul_rn_nofma(a0, a0);
  float s = fabsf(a0);
  for (int i = 8; i < 128; i += 8) {
    const float v = src[i + j];
    r = r + mul_rn_nofma(v, v);
    s = s + fabsf(v);
  }
  // exact tree: ((r0+r1)+(r2+r3))+((r4+r5)+(r6+r7)), then blk0+blk1
  r = r + __shfl_xor(r, 1, 64);
  r = r + __shfl_xor(r, 2, 64);
  r = r + __shfl_xor(r, 4, 64);
  r = r + __shfl_xor(r, 8, 64);
  s = s + __shfl_xor(s, 1, 64);
  s = s + __shfl_xor(s, 2, 64);
  s = s + __shfl_xor(s, 4, 64);
  s = s + __shfl_xor(s, 8, 64);
  if ((l & 15) == 0) {
    if (row < N_ROWS) {
      ws[WS_ZNORM + row] = r;
      // rigorous screen margin: 2*E_n + rho_max + slack (validated round 3)
      ws[WS_MARGIN + row] = 2.0e-6f * s + 4.0e-5f;
      ((unsigned int*)ws)[WS_CNT + row] = 0u;
    } else {
      ws[WS_WNORM + (row - N_ROWS)] = r;
    }
  }
  if (blockIdx.x == 0 && tid == 0) {
    ws[WS_LOSS] = 0.0f;
    ((unsigned int*)ws)[WS_OVF] = 0u;
  }
}

// FUSED single-pass screen: each block exclusively owns 128 z-rows, loops all 64
// column tiles. Per-tile: MFMA (128x128), quadrant row-max -> LDS runkey
// (ds_max_u32), append candidates (value,col) with cut = max(runkey, own quadrant
// max) - margin. Stale runkey only over-collects (superset) -> recheck filters by
// FINAL rowmax. 4 waves as 2x2 of 64x64; BK=64; XOR-swizzled LDS (0 conflicts,
// validated round 3).
__global__ __launch_bounds__(256) void gemm_screen_fused(
    const unsigned short* __restrict__ zbf, const unsigned short* __restrict__ wbf,
    float* __restrict__ ws, uint2* __restrict__ candp) {
  __shared__ __align__(16) unsigned short As[128][64];
  __shared__ __align__(16) unsigned short Bs[128][64];
  __shared__ unsigned int runkey[128];
  __shared__ float marg[128];

  const int tid = threadIdx.x;
  const int w = tid >> 6, l = tid & 63;
  const int lr = l & 15, lq = l >> 4;
  const int wr = (w >> 1) * 64, wc = (w & 1) * 64;
  const int rowBase = blockIdx.x * 128;
  const int r8 = l >> 3, slot = l & 7;

  unsigned int* cntp = (unsigned int*)ws + WS_CNT;

  if (tid < 128) {
    runkey[tid] = 0u;  // key(-inf)
    marg[tid] = ws[WS_MARGIN + rowBase + tid];
  }
  // visibility covered by the first staging __syncthreads below

  for (int ct = 0; ct < K_CODES / 128; ++ct) {
    const int colBase = ct * 128;
    f32x4 acc[4][4];
#pragma unroll
    for (int mi = 0; mi < 4; ++mi)
#pragma unroll
      for (int ni = 0; ni < 4; ++ni) acc[mi][ni] = (f32x4){0.f, 0.f, 0.f, 0.f};

    for (int c = 0; c < 4; ++c) {
      __syncthreads();
      const int doff = c * 64;  // u16 units
#pragma unroll
      for (int j = 0; j < 4; ++j) {
        const int r_l = w * 32 + j * 8 + r8;  // LDS-local row this lane feeds
        const int ga = slot ^ (r_l & 7);      // swizzled global 16B-chunk
        glds16(zbf + (size_t)(rowBase + r_l) * DIM + doff + ga * 8, &As[w * 32 + j * 8][0]);
        glds16(wbf + (size_t)(colBase + r_l) * DIM + doff + ga * 8, &Bs[w * 32 + j * 8][0]);
      }
      __syncthreads();  // drains vmcnt -> DMA complete
#pragma unroll
      for (int kk = 0; kk < 2; ++kk) {
        const int g = kk * 4 + lq;
        bf16x8 af[4], bfr[4];
#pragma unroll
        for (int mi = 0; mi < 4; ++mi) {
          const int r_l = wr + mi * 16 + lr;
          af[mi] = *(const bf16x8*)&As[r_l][(g ^ (r_l & 7)) * 8];
        }
#pragma unroll
        for (int ni = 0; ni < 4; ++ni) {
          const int r_l = wc + ni * 16 + lr;
          bfr[ni] = *(const bf16x8*)&Bs[r_l][(g ^ (r_l & 7)) * 8];
        }
#pragma unroll
        for (int mi = 0; mi < 4; ++mi)
#pragma unroll
          for (int ni = 0; ni < 4; ++ni)
            acc[mi][ni] =
                __builtin_amdgcn_mfma_f32_16x16x32_bf16(af[mi], bfr[ni], acc[mi][ni], 0, 0, 0);
      }
    }

    // ---- fused epilogue ----
    // C/D layout (validated): col = lane&15, row = (lane>>4)*4 + reg
    float mx[4][4];
#pragma unroll
    for (int mi = 0; mi < 4; ++mi)
#pragma unroll
      for (int r = 0; r < 4; ++r)
        mx[mi][r] = fmaxf(fmaxf(acc[mi][0][r], acc[mi][1][r]),
                          fmaxf(acc[mi][2][r], acc[mi][3][r]));
#pragma unroll
    for (int m = 1; m < 16; m <<= 1)
#pragma unroll
      for (int mi = 0; mi < 4; ++mi)
#pragma unroll
        for (int r = 0; r < 4; ++r)
          mx[mi][r] = fmaxf(mx[mi][r], __shfl_xor(mx[mi][r], m, 64));
    // after reduce, all lr lanes hold the quadrant (64-col) row max
    if (lr == 0) {
#pragma unroll
      for (int mi = 0; mi < 4; ++mi)
#pragma unroll
        for (int r = 0; r < 4; ++r)
          atomicMax(&runkey[wr + mi * 16 + lq * 4 + r], f2key(mx[mi][r]));
    }
    // stale-cut append: cut = max(runkey (racy read ok), own quadrant max) - margin.
    // runkey <= final max always -> append set is a superset of final candidates.
#pragma unroll
    for (int mi = 0; mi < 4; ++mi)
#pragma unroll
      for (int r = 0; r < 4; ++r) {
        const int lrow = wr + mi * 16 + lq * 4 + r;
        const float rm = fmaxf(key2f(runkey[lrow]), mx[mi][r]);
        const float cut = rm - marg[lrow];
#pragma unroll
        for (int ni = 0; ni < 4; ++ni) {
          if (acc[mi][ni][r] >= cut) {
            const int grow = rowBase + lrow;
            const int gcol = colBase + wc + ni * 16 + lr;
            const unsigned int pos = atomicAdd(&cntp[grow], 1u);
            if (pos < CAP) {
              uint2 e;
              e.x = __float_as_uint(acc[mi][ni][r]);
              e.y = (unsigned int)gcol;
              candp[(size_t)grow * CAP + pos] = e;
            }
          }
        }
      }
  }

  __syncthreads();
  if (tid < 128) ((unsigned int*)ws)[WS_ROWMAX + rowBase + tid] = runkey[tid];
}

// One thread per row: filter stored candidates by FINAL rowmax - margin, then
// exact np distance over survivors; overflow rows queued for fallback.
__global__ void recheck_kernel(const float* __restrict__ z, const float* __restrict__ W,
                               float* __restrict__ ws, const uint2* __restrict__ candp,
                               float* __restrict__ out) {
  const int row = blockIdx.x * blockDim.x + threadIdx.x;
  const unsigned int cv = ((const unsigned int*)ws)[WS_CNT + row];
  if (cv > CAP) {
    const unsigned int p = atomicAdd(&((unsigned int*)ws)[WS_OVF], 1u);
    ((unsigned int*)ws)[WS_OVFLIST + p] = (unsigned int)row;
    return;
  }
  const float cut =
      key2f(((const unsigned int*)ws)[WS_ROWMAX + row]) - ws[WS_MARGIN + row];
  const float zn = ws[WS_ZNORM + row];
  const float* zp = z + (size_t)row * DIM;
  float best = 3.4e38f;
  int bi = K_CODES;
  for (unsigned int j = 0; j < cv; ++j) {
    const uint2 e = candp[(size_t)row * CAP + j];
    if (__uint_as_float(e.x) < cut) continue;  // below final cut: cannot be argmin
    const int k = (int)e.y;
    const float m = dot_chain(zp, W + (size_t)k * DIM);
    const float dist = (zn + ws[WS_WNORM + k]) - 2.0f * m;
    if (dist < best || (dist == best && k < bi)) { best = dist; bi = k; }
  }
  out[IDX_OFF + row] = (float)bi;
}

// Block-cooperative exact full scan for overflow rows (expected ~0 rows).
__global__ void fallback_kernel(const float* __restrict__ z, const float* __restrict__ W,
                                float* __restrict__ ws, float* __restrict__ out) {
  __shared__ float sd[256];
  __shared__ int si[256];
  const unsigned int n = ((const unsigned int*)ws)[WS_OVF];
  for (unsigned int item = blockIdx.x; item < n; item += gridDim.x) {
    const int row = (int)((const unsigned int*)ws)[WS_OVFLIST + item];
    const float zn = ws[WS_ZNORM + row];
    const float* zp = z + (size_t)row * DIM;
    float best = 3.4e38f;
    int bi = K_CODES;
    for (int k = threadIdx.x; k < K_CODES; k += 256) {
      const float m = dot_chain(zp, W + (size_t)k * DIM);
      const float dist = (zn + ws[WS_WNORM + k]) - 2.0f * m;
      if (dist < best) { best = dist; bi = k; }  // ascending k: strict < keeps lowest
    }
    sd[threadIdx.x] = best;
    si[threadIdx.x] = bi;
    __syncthreads();
    for (int s = 128; s > 0; s >>= 1) {
      if (threadIdx.x < s) {
        if (sd[threadIdx.x + s] < sd[threadIdx.x] ||
            (sd[threadIdx.x + s] == sd[threadIdx.x] && si[threadIdx.x + s] < si[threadIdx.x])) {
          sd[threadIdx.x] = sd[threadIdx.x + s];
          si[threadIdx.x] = si[threadIdx.x + s];
        }
      }
      __syncthreads();
    }
    if (threadIdx.x == 0) out[IDX_OFF + row] = (float)si[0];
    __syncthreads();
  }
}

// 64 rows/block: gather W[idx], quantized_st = z + (q - z), loss partial sums.
__global__ void gather_loss_kernel(const float* __restrict__ z, const float* __restrict__ W,
                                   float* __restrict__ out, float* __restrict__ ws) {
  const int tid = threadIdx.x;
  const int rowBase = blockIdx.x * 64;
  float lsum = 0.0f;
  for (int p = 0; p < 16; ++p) {
    const int row = rowBase + p * 4 + (tid >> 6);
    const int c4 = tid & 63;
    const int idx = (int)out[IDX_OFF + row];
    const float4 zv = *(const float4*)(z + (size_t)row * DIM + c4 * 4);
    const float4 qv = *(const float4*)(W + (size_t)idx * DIM + c4 * 4);
    float4 t, o;
    t.x = qv.x - zv.x; t.y = qv.y - zv.y; t.z = qv.z - zv.z; t.w = qv.w - zv.w;
    o.x = zv.x + t.x;  o.y = zv.y + t.y;  o.z = zv.z + t.z;  o.w = zv.w + t.w;
    *(float4*)(out + (size_t)row * DIM + c4 * 4) = o;
    lsum += t.x * t.x + t.y * t.y + t.z * t.z + t.w * t.w;
  }
#pragma unroll
  for (int m = 1; m < 64; m <<= 1) lsum += __shfl_xor(lsum, m, 64);
  __shared__ float part[4];
  if ((tid & 63) == 0) part[tid >> 6] = lsum;
  __syncthreads();
  if (tid == 0) atomicAdd(&ws[WS_LOSS], (part[0] + part[1]) + (part[2] + part[3]));
}

__global__ void finalize_kernel(const float* __restrict__ ws, float* __restrict__ out) {
  if (threadIdx.x == 0 && blockIdx.x == 0) {
    const float mean = ws[WS_LOSS] / (float)(N_ROWS * DIM);
    out[LOSS_OFF] = mean + 0.25f * mean;
  }
}

extern "C" void kernel_launch(void* const* d_in, const int* in_sizes, int n_in,
                              void* d_out, int out_size, void* d_ws, size_t ws_size,
                              hipStream_t stream) {
  (void)in_sizes; (void)n_in; (void)out_size; (void)ws_size;
  const float* z = (const float*)d_in[0];
  const float* W = (const float*)d_in[1];
  float* out = (float*)d_out;
  float* ws = (float*)d_ws;
  unsigned short* outu = (unsigned short*)d_out;
  const unsigned short* wbf = outu + OUT_WBF_U16;
  const unsigned short* zbf = outu + OUT_ZBF_U16;
  uint2* candp = (uint2*)((float*)d_out + OUT_CAND_F);

  hipLaunchKernelGGL(precvt_kernel, dim3(18432), dim3(256), 0, stream, z, W, outu);
  hipLaunchKernelGGL(norms_kernel, dim3((N_ROWS + K_CODES) / 16), dim3(256), 0, stream,
                     z, W, ws);
  hipLaunchKernelGGL(gemm_screen_fused, dim3(N_ROWS / 128), dim3(256), 0, stream,
                     zbf, wbf, ws, candp);
  hipLaunchKernelGGL(recheck_kernel, dim3(N_ROWS / 256), dim3(256), 0, stream,
                     z, W, ws, candp, out);
  hipLaunchKernelGGL(fallback_kernel, dim3(128), dim3(256), 0, stream, z, W, ws, out);
  hipLaunchKernelGGL(gather_loss_kernel, dim3(N_ROWS / 64), dim3(256), 0, stream,
                     z, W, out, ws);
  hipLaunchKernelGGL(finalize_kernel, dim3(1), dim3(64), 0, stream, ws, out);
}

// Round 5
// 1698.191 us; speedup vs baseline: 1.1887x; 1.1887x over previous
//
#include <hip/hip_runtime.h>

#define N_ROWS 65536
#define K_CODES 8192
#define DIM 256
#define CAP 48

// d_out layout (floats): [quantized_st 65536*256][loss 1][indices 65536]
#define LOSS_OFF (N_ROWS * DIM)
#define IDX_OFF (LOSS_OFF + 1)
// scratch inside d_out's quantized region (consumed before gather overwrites):
#define OUT_WBF_U16 0              // W_bf: 8192*256 u16  (4 MB)
#define OUT_ZBF_U16 2097152        // z_bf: 65536*256 u16 (32 MB)
#define OUT_CAND_F 9437184         // cand: 65536*48 uint2 (25.2 MB); ends 15728640 < 16777216

// d_ws layout (4-byte units), ~1.3 MB total
#define WS_LOSS 0
#define WS_ZNORM 64
#define WS_WNORM (WS_ZNORM + N_ROWS)
#define WS_MARGIN (WS_WNORM + K_CODES)
#define WS_CUT0 (WS_MARGIN + N_ROWS)
#define WS_CNT (WS_CUT0 + N_ROWS)       // uint
#define WS_OVF (WS_CNT + N_ROWS)        // uint counter
#define WS_OVFLIST (WS_OVF + 1)         // uint, up to N_ROWS

typedef __bf16 bf16x8 __attribute__((ext_vector_type(8)));
typedef float f32x4 __attribute__((ext_vector_type(4)));

// ---------- numerics helpers ----------

__device__ __forceinline__ float mul_rn_nofma(float a, float b) {
  float r;
  asm("v_mul_f32 %0, %1, %2" : "=v"(r) : "v"(a), "v"(b));
  return r;
}

// fp32 -> bf16 bits, RNE (error <= 2^-8 rel; the margin derivation assumes this).
__device__ __forceinline__ unsigned int f2bf(float f) {
  unsigned int u = __float_as_uint(f);
  return (u + 0x7FFFu + ((u >> 16) & 1u)) >> 16;
}

// Exact np matmul replica: single ascending-d fmaf chain (bit-proven rounds 1-4).
__device__ float dot_chain(const float* __restrict__ zp, const float* __restrict__ wp) {
  float acc = 0.0f;
#pragma unroll 8
  for (int d4 = 0; d4 < 64; ++d4) {
    const float4 a = *(const float4*)(zp + d4 * 4);
    const float4 b = *(const float4*)(wp + d4 * 4);
    acc = fmaf(a.x, b.x, acc);
    acc = fmaf(a.y, b.y, acc);
    acc = fmaf(a.z, b.z, acc);
    acc = fmaf(a.w, b.w, acc);
  }
  return acc;
}

// global -> LDS 16B DMA (wave-uniform LDS base + lane*16).
__device__ __forceinline__ void glds16(const void* g, void* l) {
  __builtin_amdgcn_global_load_lds(
      (const __attribute__((address_space(1))) void*)(unsigned long long)(size_t)g,
      (__attribute__((address_space(3))) void*)(unsigned int)(size_t)l, 16, 0, 0);
}

// ---------- kernels ----------

// Convert W then z to bf16 into the out-region scratch. One float4 per thread.
__global__ void precvt_kernel(const float* __restrict__ z, const float* __restrict__ W,
                              unsigned short* __restrict__ outu) {
  const int t = blockIdx.x * blockDim.x + threadIdx.x;  // 0 .. 4718591
  const int WQ = (K_CODES * DIM) / 4;                   // 524288
  const float4 v = (t < WQ) ? ((const float4*)W)[t] : ((const float4*)z)[t - WQ];
  uint2 p;
  p.x = f2bf(v.x) | (f2bf(v.y) << 16);
  p.y = f2bf(v.z) | (f2bf(v.w) << 16);
  ((uint2*)outu)[t] = p;
}

// Coalesced norms: wave handles 4 rows; 16 lanes/row replicate numpy's pairwise
// tree exactly (8 stride-8 accumulators per 128-block, fixed combine order).
// Also computes the fixed statistical screen cut: cut0 = 3.05*||z||*sigma_w - margin.
// sigma_w = (2/8192)/sqrt(12) = 7.0467e-5 (W ~ U(+-1/8192)). Wrong assumption ->
// rows fail the recheck rigor test and take the exact fallback (slow, never wrong).
__global__ void norms_kernel(const float* __restrict__ z, const float* __restrict__ W,
                             float* __restrict__ ws) {
  const int tid = threadIdx.x;
  const int l = tid & 63, w = tid >> 6;
  const int j = l & 7, b = (l >> 3) & 1, rw = l >> 4;
  const int row = blockIdx.x * 16 + w * 4 + rw;  // 0 .. 73727
  const float* src = (row < N_ROWS) ? (z + (size_t)row * DIM + b * 128)
                                    : (W + (size_t)(row - N_ROWS) * DIM + b * 128);
  float a0 = src[j];
  float r = mul_rn_nofma(a0, a0);
  float s = fabsf(a0);
  for (int i = 8; i < 128; i += 8) {
    const float v = src[i + j];
    r = r + mul_rn_nofma(v, v);
    s = s + fabsf(v);
  }
  // exact tree: ((r0+r1)+(r2+r3))+((r4+r5)+(r6+r7)), then blk0+blk1
  r = r + __shfl_xor(r, 1, 64);
  r = r + __shfl_xor(r, 2, 64);
  r = r + __shfl_xor(r, 4, 64);
  r = r + __shfl_xor(r, 8, 64);
  s = s + __shfl_xor(s, 1, 64);
  s = s + __shfl_xor(s, 2, 64);
  s = s + __shfl_xor(s, 4, 64);
  s = s + __shfl_xor(s, 8, 64);
  if ((l & 15) == 0) {
    if (row < N_ROWS) {
      ws[WS_ZNORM + row] = r;
      // rigorous screen margin: 2*E_n + rho_max + slack (validated rounds 3-4)
      const float margin = 2.0e-6f * s + 4.0e-5f;
      ws[WS_MARGIN + row] = margin;
      ws[WS_CUT0 + row] = 3.05f * sqrtf(r) * 7.0467e-5f - margin;
      ((unsigned int*)ws)[WS_CNT + row] = 0u;
    } else {
      ws[WS_WNORM + (row - N_ROWS)] = r;
    }
  }
  if (blockIdx.x == 0 && tid == 0) {
    ws[WS_LOSS] = 0.0f;
    ((unsigned int*)ws)[WS_OVF] = 0u;
  }
}

// Single-pass bf16 MFMA screen GEMM: round-3's proven 2D-grid structure
// (128x128 tile/block, 4 waves as 2x2 of 64x64, BK=64, XOR-swizzled LDS,
// global_load_lds staging — 0 bank conflicts, 33% MfmaUtil measured), but with
// the fixed per-row cut0 known up front: epilogue is append-only (no reduce,
// no atomicMax, no second pass). Stores (acc_bits, col) for the recheck filter.
__global__ __launch_bounds__(256) void gemm_screen_kernel(
    const unsigned short* __restrict__ zbf, const unsigned short* __restrict__ wbf,
    float* __restrict__ ws, uint2* __restrict__ candp) {
  __shared__ __align__(16) unsigned short As[128][64];
  __shared__ __align__(16) unsigned short Bs[128][64];
  __shared__ float cutbuf[128];

  const int tid = threadIdx.x;
  const int w = tid >> 6, l = tid & 63;
  const int lr = l & 15, lq = l >> 4;
  const int wr = (w >> 1) * 64, wc = (w & 1) * 64;
  const int rowBase = blockIdx.y * 128, colBase = blockIdx.x * 128;
  const int r8 = l >> 3, slot = l & 7;

  unsigned int* cntp = (unsigned int*)ws + WS_CNT;

  if (tid < 128) cutbuf[tid] = ws[WS_CUT0 + rowBase + tid];
  // visibility covered by the first staging __syncthreads below

  f32x4 acc[4][4];
#pragma unroll
  for (int mi = 0; mi < 4; ++mi)
#pragma unroll
    for (int ni = 0; ni < 4; ++ni) acc[mi][ni] = (f32x4){0.f, 0.f, 0.f, 0.f};

  for (int c = 0; c < 4; ++c) {
    __syncthreads();
    const int doff = c * 64;  // u16 units
#pragma unroll
    for (int j = 0; j < 4; ++j) {
      const int r_l = w * 32 + j * 8 + r8;  // LDS-local row this lane feeds
      const int ga = slot ^ (r_l & 7);      // swizzled global 16B-chunk
      glds16(zbf + (size_t)(rowBase + r_l) * DIM + doff + ga * 8, &As[w * 32 + j * 8][0]);
      glds16(wbf + (size_t)(colBase + r_l) * DIM + doff + ga * 8, &Bs[w * 32 + j * 8][0]);
    }
    __syncthreads();  // drains vmcnt -> DMA complete
#pragma unroll
    for (int kk = 0; kk < 2; ++kk) {
      const int g = kk * 4 + lq;
      bf16x8 af[4], bfr[4];
#pragma unroll
      for (int mi = 0; mi < 4; ++mi) {
        const int r_l = wr + mi * 16 + lr;
        af[mi] = *(const bf16x8*)&As[r_l][(g ^ (r_l & 7)) * 8];
      }
#pragma unroll
      for (int ni = 0; ni < 4; ++ni) {
        const int r_l = wc + ni * 16 + lr;
        bfr[ni] = *(const bf16x8*)&Bs[r_l][(g ^ (r_l & 7)) * 8];
      }
#pragma unroll
      for (int mi = 0; mi < 4; ++mi)
#pragma unroll
        for (int ni = 0; ni < 4; ++ni)
          acc[mi][ni] =
              __builtin_amdgcn_mfma_f32_16x16x32_bf16(af[mi], bfr[ni], acc[mi][ni], 0, 0, 0);
    }
  }

  // Append-only epilogue. C/D layout (validated): col = lane&15, row = (lane>>4)*4 + reg
#pragma unroll
  for (int mi = 0; mi < 4; ++mi)
#pragma unroll
    for (int r = 0; r < 4; ++r) {
      const int lrow = wr + mi * 16 + lq * 4 + r;
      const float cut = cutbuf[lrow];
#pragma unroll
      for (int ni = 0; ni < 4; ++ni) {
        if (acc[mi][ni][r] >= cut) {
          const int grow = rowBase + lrow;
          const int gcol = colBase + wc + ni * 16 + lr;
          const unsigned int pos = atomicAdd(&cntp[grow], 1u);
          if (pos < CAP) {
            uint2 e;
            e.x = __float_as_uint(acc[mi][ni][r]);
            e.y = (unsigned int)gcol;
            candp[(size_t)grow * CAP + pos] = e;
          }
        }
      }
    }
}

// One thread per row. Rigor gate: candmax - margin >= cut0 proves the stored set
// superset-covers {acc >= accmax - margin} (the round-3-validated candidate set);
// otherwise exact fallback. Then filter by candmax - margin and np-chain survivors.
__global__ void recheck_kernel(const float* __restrict__ z, const float* __restrict__ W,
                               float* __restrict__ ws, const uint2* __restrict__ candp,
                               float* __restrict__ out) {
  const int row = blockIdx.x * blockDim.x + threadIdx.x;
  const unsigned int cv = ((const unsigned int*)ws)[WS_CNT + row];
  const float margin = ws[WS_MARGIN + row];
  const float cut0 = ws[WS_CUT0 + row];
  bool fb = (cv == 0u) || (cv > CAP);
  float candmax = -3.4e38f;
  if (!fb) {
    for (unsigned int j = 0; j < cv; ++j)
      candmax = fmaxf(candmax, __uint_as_float(candp[(size_t)row * CAP + j].x));
    if (candmax - margin < cut0) fb = true;  // cannot prove superset -> exact scan
  }
  if (fb) {
    const unsigned int p = atomicAdd(&((unsigned int*)ws)[WS_OVF], 1u);
    ((unsigned int*)ws)[WS_OVFLIST + p] = (unsigned int)row;
    return;
  }
  const float fcut = candmax - margin;
  const float zn = ws[WS_ZNORM + row];
  const float* zp = z + (size_t)row * DIM;
  float best = 3.4e38f;
  int bi = K_CODES;
  for (unsigned int j = 0; j < cv; ++j) {
    const uint2 e = candp[(size_t)row * CAP + j];
    if (__uint_as_float(e.x) < fcut) continue;  // below final cut: cannot be argmin
    const int k = (int)e.y;
    const float m = dot_chain(zp, W + (size_t)k * DIM);
    const float dist = (zn + ws[WS_WNORM + k]) - 2.0f * m;
    if (dist < best || (dist == best && k < bi)) { best = dist; bi = k; }
  }
  out[IDX_OFF + row] = (float)bi;
}

// Block-cooperative exact full scan for queued rows (expected ~5 rows).
__global__ void fallback_kernel(const float* __restrict__ z, const float* __restrict__ W,
                                float* __restrict__ ws, float* __restrict__ out) {
  __shared__ float sd[256];
  __shared__ int si[256];
  const unsigned int n = ((const unsigned int*)ws)[WS_OVF];
  for (unsigned int item = blockIdx.x; item < n; item += gridDim.x) {
    const int row = (int)((const unsigned int*)ws)[WS_OVFLIST + item];
    const float zn = ws[WS_ZNORM + row];
    const float* zp = z + (size_t)row * DIM;
    float best = 3.4e38f;
    int bi = K_CODES;
    for (int k = threadIdx.x; k < K_CODES; k += 256) {
      const float m = dot_chain(zp, W + (size_t)k * DIM);
      const float dist = (zn + ws[WS_WNORM + k]) - 2.0f * m;
      if (dist < best) { best = dist; bi = k; }  // ascending k: strict < keeps lowest
    }
    sd[threadIdx.x] = best;
    si[threadIdx.x] = bi;
    __syncthreads();
    for (int s = 128; s > 0; s >>= 1) {
      if (threadIdx.x < s) {
        if (sd[threadIdx.x + s] < sd[threadIdx.x] ||
            (sd[threadIdx.x + s] == sd[threadIdx.x] && si[threadIdx.x + s] < si[threadIdx.x])) {
          sd[threadIdx.x] = sd[threadIdx.x + s];
          si[threadIdx.x] = si[threadIdx.x + s];
        }
      }
      __syncthreads();
    }
    if (threadIdx.x == 0) out[IDX_OFF + row] = (float)si[0];
    __syncthreads();
  }
}

// 64 rows/block: gather W[idx], quantized_st = z + (q - z), loss partial sums.
__global__ void gather_loss_kernel(const float* __restrict__ z, const float* __restrict__ W,
                                   float* __restrict__ out, float* __restrict__ ws) {
  const int tid = threadIdx.x;
  const int rowBase = blockIdx.x * 64;
  float lsum = 0.0f;
  for (int p = 0; p < 16; ++p) {
    const int row = rowBase + p * 4 + (tid >> 6);
    const int c4 = tid & 63;
    const int idx = (int)out[IDX_OFF + row];
    const float4 zv = *(const float4*)(z + (size_t)row * DIM + c4 * 4);
    const float4 qv = *(const float4*)(W + (size_t)idx * DIM + c4 * 4);
    float4 t, o;
    t.x = qv.x - zv.x; t.y = qv.y - zv.y; t.z = qv.z - zv.z; t.w = qv.w - zv.w;
    o.x = zv.x + t.x;  o.y = zv.y + t.y;  o.z = zv.z + t.z;  o.w = zv.w + t.w;
    *(float4*)(out + (size_t)row * DIM + c4 * 4) = o;
    lsum += t.x * t.x + t.y * t.y + t.z * t.z + t.w * t.w;
  }
#pragma unroll
  for (int m = 1; m < 64; m <<= 1) lsum += __shfl_xor(lsum, m, 64);
  __shared__ float part[4];
  if ((tid & 63) == 0) part[tid >> 6] = lsum;
  __syncthreads();
  if (tid == 0) atomicAdd(&ws[WS_LOSS], (part[0] + part[1]) + (part[2] + part[3]));
}

__global__ void finalize_kernel(const float* __restrict__ ws, float* __restrict__ out) {
  if (threadIdx.x == 0 && blockIdx.x == 0) {
    const float mean = ws[WS_LOSS] / (float)(N_ROWS * DIM);
    out[LOSS_OFF] = mean + 0.25f * mean;
  }
}

extern "C" void kernel_launch(void* const* d_in, const int* in_sizes, int n_in,
                              void* d_out, int out_size, void* d_ws, size_t ws_size,
                              hipStream_t stream) {
  (void)in_sizes; (void)n_in; (void)out_size; (void)ws_size;
  const float* z = (const float*)d_in[0];
  const float* W = (const float*)d_in[1];
  float* out = (float*)d_out;
  float* ws = (float*)d_ws;
  unsigned short* outu = (unsigned short*)d_out;
  const unsigned short* wbf = outu + OUT_WBF_U16;
  const unsigned short* zbf = outu + OUT_ZBF_U16;
  uint2* candp = (uint2*)((float*)d_out + OUT_CAND_F);

  hipLaunchKernelGGL(precvt_kernel, dim3(18432), dim3(256), 0, stream, z, W, outu);
  hipLaunchKernelGGL(norms_kernel, dim3((N_ROWS + K_CODES) / 16), dim3(256), 0, stream,
                     z, W, ws);
  hipLaunchKernelGGL(gemm_screen_kernel, dim3(K_CODES / 128, N_ROWS / 128), dim3(256),
                     0, stream, zbf, wbf, ws, candp);
  hipLaunchKernelGGL(recheck_kernel, dim3(N_ROWS / 256), dim3(256), 0, stream,
                     z, W, ws, candp, out);
  hipLaunchKernelGGL(fallback_kernel, dim3(128), dim3(256), 0, stream, z, W, ws, out);
  hipLaunchKernelGGL(gather_loss_kernel, dim3(N_ROWS / 64), dim3(256), 0, stream,
                     z, W, out, ws);
  hipLaunchKernelGGL(finalize_kernel, dim3(1), dim3(64), 0, stream, ws, out);
}

// Round 6
// 1040.827 us; speedup vs baseline: 1.9395x; 1.6316x over previous
//
#include <hip/hip_runtime.h>

#define N_ROWS 65536
#define K_CODES 8192
#define DIM 256
#define CAP 56

// d_out layout (floats): [quantized_st 65536*256][loss 1][indices 65536]
#define LOSS_OFF (N_ROWS * DIM)
#define IDX_OFF (LOSS_OFF + 1)
// scratch inside d_out's quantized region (consumed before gather overwrites):
#define OUT_WBF_U16 0              // W_bf: 8192*256 u16  (4 MB)
#define OUT_ZBF_U16 2097152        // z_bf: 65536*256 u16 (32 MB)
#define OUT_CAND_F 9437184         // cand: 65536*56 uint2 (29.36 MB); ends exactly at 16777216

// d_ws layout (4-byte units), ~1.85 MB total
#define WS_LOSS 0
#define WS_ZNORM 64
#define WS_WNORM (WS_ZNORM + N_ROWS)
#define WS_MARGIN (WS_WNORM + K_CODES)
#define WS_CUT0 (WS_MARGIN + N_ROWS)
#define WS_CNT (WS_CUT0 + N_ROWS)       // uint
#define WS_OVF (WS_CNT + N_ROWS)        // uint counter
#define WS_OVFLIST (WS_OVF + 1)         // uint, up to N_ROWS
#define WS_SLOT (((WS_OVFLIST + N_ROWS) + 1) & ~1)  // u64 per row (8B aligned), 2*N_ROWS u32

typedef __bf16 bf16x8 __attribute__((ext_vector_type(8)));
typedef float f32x4 __attribute__((ext_vector_type(4)));

// ---------- numerics helpers ----------

__device__ __forceinline__ float mul_rn_nofma(float a, float b) {
  float r;
  asm("v_mul_f32 %0, %1, %2" : "=v"(r) : "v"(a), "v"(b));
  return r;
}

// fp32 -> bf16 bits, RNE (error <= 2^-8 rel; the margin derivation assumes this).
__device__ __forceinline__ unsigned int f2bf(float f) {
  unsigned int u = __float_as_uint(f);
  return (u + 0x7FFFu + ((u >> 16) & 1u)) >> 16;
}

// Exact np matmul replica: single ascending-d fmaf chain (bit-proven rounds 1-5).
__device__ float dot_chain(const float* __restrict__ zp, const float* __restrict__ wp) {
  float acc = 0.0f;
#pragma unroll 8
  for (int d4 = 0; d4 < 64; ++d4) {
    const float4 a = *(const float4*)(zp + d4 * 4);
    const float4 b = *(const float4*)(wp + d4 * 4);
    acc = fmaf(a.x, b.x, acc);
    acc = fmaf(a.y, b.y, acc);
    acc = fmaf(a.z, b.z, acc);
    acc = fmaf(a.w, b.w, acc);
  }
  return acc;
}

// global -> LDS 16B DMA (wave-uniform LDS base + lane*16).
__device__ __forceinline__ void glds16(const void* g, void* l) {
  __builtin_amdgcn_global_load_lds(
      (const __attribute__((address_space(1))) void*)(unsigned long long)(size_t)g,
      (__attribute__((address_space(3))) void*)(unsigned int)(size_t)l, 16, 0, 0);
}

// ---------- kernels ----------

// Convert W then z to bf16 into the out-region scratch. One float4 per thread.
__global__ void precvt_kernel(const float* __restrict__ z, const float* __restrict__ W,
                              unsigned short* __restrict__ outu) {
  const int t = blockIdx.x * blockDim.x + threadIdx.x;  // 0 .. 4718591
  const int WQ = (K_CODES * DIM) / 4;                   // 524288
  const float4 v = (t < WQ) ? ((const float4*)W)[t] : ((const float4*)z)[t - WQ];
  uint2 p;
  p.x = f2bf(v.x) | (f2bf(v.y) << 16);
  p.y = f2bf(v.z) | (f2bf(v.w) << 16);
  ((uint2*)outu)[t] = p;
}

// Coalesced norms; also the fixed statistical screen cut:
// cut0 = 3.10*||z||*sigma_w - margin, sigma_w = (2/8192)/sqrt(12) = 7.0467e-5.
// Append rate: lambda = 8192*Phic(3.10 - margin/sigma ~= 2.70) ~= 28 (CAP=56,
// P(overflow) ~3e-5/row). Gate-fail P(max < 3.10 sigma) = e^-7.9 ~= 3.6e-4 (~24 rows).
// Wrong distribution assumption -> rows fail the recheck gate -> exact fallback.
__global__ void norms_kernel(const float* __restrict__ z, const float* __restrict__ W,
                             float* __restrict__ ws) {
  const int tid = threadIdx.x;
  const int l = tid & 63, w = tid >> 6;
  const int j = l & 7, b = (l >> 3) & 1, rw = l >> 4;
  const int row = blockIdx.x * 16 + w * 4 + rw;  // 0 .. 73727
  const float* src = (row < N_ROWS) ? (z + (size_t)row * DIM + b * 128)
                                    : (W + (size_t)(row - N_ROWS) * DIM + b * 128);
  float a0 = src[j];
  float r = mul_rn_nofma(a0, a0);
  float s = fabsf(a0);
  for (int i = 8; i < 128; i += 8) {
    const float v = src[i + j];
    r = r + mul_rn_nofma(v, v);
    s = s + fabsf(v);
  }
  // exact numpy pairwise tree: ((r0+r1)+(r2+r3))+((r4+r5)+(r6+r7)), then blk0+blk1
  r = r + __shfl_xor(r, 1, 64);
  r = r + __shfl_xor(r, 2, 64);
  r = r + __shfl_xor(r, 4, 64);
  r = r + __shfl_xor(r, 8, 64);
  s = s + __shfl_xor(s, 1, 64);
  s = s + __shfl_xor(s, 2, 64);
  s = s + __shfl_xor(s, 4, 64);
  s = s + __shfl_xor(s, 8, 64);
  if ((l & 15) == 0) {
    if (row < N_ROWS) {
      ws[WS_ZNORM + row] = r;
      // rigorous screen margin: 2*E_n + rho_max + slack (validated rounds 3-5)
      const float margin = 2.0e-6f * s + 4.0e-5f;
      ws[WS_MARGIN + row] = margin;
      ws[WS_CUT0 + row] = 3.10f * sqrtf(r) * 7.0467e-5f - margin;
      ((unsigned int*)ws)[WS_CNT + row] = 0u;
    } else {
      ws[WS_WNORM + (row - N_ROWS)] = r;
    }
  }
  if (blockIdx.x == 0 && tid == 0) {
    ws[WS_LOSS] = 0.0f;
    ((unsigned int*)ws)[WS_OVF] = 0u;
  }
}

// Single-pass bf16 MFMA screen GEMM (round-3 proven structure: 128x128/block,
// 2x2 waves of 64x64, BK=64, XOR-swizzled LDS, global_load_lds, 0 conflicts).
// Append-only epilogue against the fixed per-row cut0; stores (acc_bits, col).
__global__ __launch_bounds__(256) void gemm_screen_kernel(
    const unsigned short* __restrict__ zbf, const unsigned short* __restrict__ wbf,
    float* __restrict__ ws, uint2* __restrict__ candp) {
  __shared__ __align__(16) unsigned short As[128][64];
  __shared__ __align__(16) unsigned short Bs[128][64];
  __shared__ float cutbuf[128];

  const int tid = threadIdx.x;
  const int w = tid >> 6, l = tid & 63;
  const int lr = l & 15, lq = l >> 4;
  const int wr = (w >> 1) * 64, wc = (w & 1) * 64;
  const int rowBase = blockIdx.y * 128, colBase = blockIdx.x * 128;
  const int r8 = l >> 3, slot = l & 7;

  unsigned int* cntp = (unsigned int*)ws + WS_CNT;

  if (tid < 128) cutbuf[tid] = ws[WS_CUT0 + rowBase + tid];
  // visibility covered by the first staging __syncthreads below

  f32x4 acc[4][4];
#pragma unroll
  for (int mi = 0; mi < 4; ++mi)
#pragma unroll
    for (int ni = 0; ni < 4; ++ni) acc[mi][ni] = (f32x4){0.f, 0.f, 0.f, 0.f};

  for (int c = 0; c < 4; ++c) {
    __syncthreads();
    const int doff = c * 64;  // u16 units
#pragma unroll
    for (int j = 0; j < 4; ++j) {
      const int r_l = w * 32 + j * 8 + r8;  // LDS-local row this lane feeds
      const int ga = slot ^ (r_l & 7);      // swizzled global 16B-chunk
      glds16(zbf + (size_t)(rowBase + r_l) * DIM + doff + ga * 8, &As[w * 32 + j * 8][0]);
      glds16(wbf + (size_t)(colBase + r_l) * DIM + doff + ga * 8, &Bs[w * 32 + j * 8][0]);
    }
    __syncthreads();  // drains vmcnt -> DMA complete
#pragma unroll
    for (int kk = 0; kk < 2; ++kk) {
      const int g = kk * 4 + lq;
      bf16x8 af[4], bfr[4];
#pragma unroll
      for (int mi = 0; mi < 4; ++mi) {
        const int r_l = wr + mi * 16 + lr;
        af[mi] = *(const bf16x8*)&As[r_l][(g ^ (r_l & 7)) * 8];
      }
#pragma unroll
      for (int ni = 0; ni < 4; ++ni) {
        const int r_l = wc + ni * 16 + lr;
        bfr[ni] = *(const bf16x8*)&Bs[r_l][(g ^ (r_l & 7)) * 8];
      }
#pragma unroll
      for (int mi = 0; mi < 4; ++mi)
#pragma unroll
        for (int ni = 0; ni < 4; ++ni)
          acc[mi][ni] =
              __builtin_amdgcn_mfma_f32_16x16x32_bf16(af[mi], bfr[ni], acc[mi][ni], 0, 0, 0);
    }
  }

  // Append-only epilogue. C/D layout (validated): col = lane&15, row = (lane>>4)*4 + reg
#pragma unroll
  for (int mi = 0; mi < 4; ++mi)
#pragma unroll
    for (int r = 0; r < 4; ++r) {
      const int lrow = wr + mi * 16 + lq * 4 + r;
      const float cut = cutbuf[lrow];
#pragma unroll
      for (int ni = 0; ni < 4; ++ni) {
        if (acc[mi][ni][r] >= cut) {
          const int grow = rowBase + lrow;
          const int gcol = colBase + wc + ni * 16 + lr;
          const unsigned int pos = atomicAdd(&cntp[grow], 1u);
          if (pos < CAP) {
            uint2 e;
            e.x = __float_as_uint(acc[mi][ni][r]);
            e.y = (unsigned int)gcol;
            candp[(size_t)grow * CAP + pos] = e;
          }
        }
      }
    }
}

// One thread per row. Rigor gate: candmax - margin >= cut0 proves the stored set
// superset-covers {acc >= accmax - margin}; otherwise queue for exact fallback
// (also init the row's u64 argmin slot). Filter survivors, np-chain each.
__global__ void recheck_kernel(const float* __restrict__ z, const float* __restrict__ W,
                               float* __restrict__ ws, const uint2* __restrict__ candp,
                               float* __restrict__ out) {
  const int row = blockIdx.x * blockDim.x + threadIdx.x;
  const unsigned int cv = ((const unsigned int*)ws)[WS_CNT + row];
  const float margin = ws[WS_MARGIN + row];
  const float cut0 = ws[WS_CUT0 + row];
  bool fb = (cv == 0u) || (cv > CAP);
  float candmax = -3.4e38f;
  if (!fb) {
    for (unsigned int j = 0; j < cv; ++j)
      candmax = fmaxf(candmax, __uint_as_float(candp[(size_t)row * CAP + j].x));
    if (candmax - margin < cut0) fb = true;  // cannot prove superset -> exact scan
  }
  if (fb) {
    ((unsigned long long*)((unsigned int*)ws + WS_SLOT))[row] = ~0ull;
    const unsigned int p = atomicAdd(&((unsigned int*)ws)[WS_OVF], 1u);
    ((unsigned int*)ws)[WS_OVFLIST + p] = (unsigned int)row;
    return;
  }
  const float fcut = candmax - margin;
  const float zn = ws[WS_ZNORM + row];
  const float* zp = z + (size_t)row * DIM;
  float best = 3.4e38f;
  int bi = K_CODES;
  for (unsigned int j = 0; j < cv; ++j) {
    const uint2 e = candp[(size_t)row * CAP + j];
    if (__uint_as_float(e.x) < fcut) continue;  // below final cut: cannot be argmin
    const int k = (int)e.y;
    const float m = dot_chain(zp, W + (size_t)k * DIM);
    const float dist = (zn + ws[WS_WNORM + k]) - 2.0f * m;
    if (dist < best || (dist == best && k < bi)) { best = dist; bi = k; }
  }
  out[IDX_OFF + row] = (float)bi;
}

// Grid-parallel exact fallback: work item = (queued row, 256-code chunk). Each
// thread one code -> exact np dist; block-reduce min; u64 atomicMin combine.
// dist >= 255 > 0 always, so the packed key (dist_bits<<32 | k) orders exactly;
// ties resolve to lowest k (np.argmin semantics). Flat cost in row count.
__global__ void fallback_compute(const float* __restrict__ z, const float* __restrict__ W,
                                 float* __restrict__ ws) {
  __shared__ unsigned long long part[4];
  const unsigned int n = ((const unsigned int*)ws)[WS_OVF];
  unsigned long long* slots = (unsigned long long*)((unsigned int*)ws + WS_SLOT);
  const unsigned int total = n * 32u;
  for (unsigned int item = blockIdx.x; item < total; item += gridDim.x) {
    const int row = (int)((const unsigned int*)ws)[WS_OVFLIST + (item >> 5)];
    const int k = (int)(item & 31u) * 256 + threadIdx.x;
    const float zn = ws[WS_ZNORM + row];
    const float m = dot_chain(z + (size_t)row * DIM, W + (size_t)k * DIM);
    const float dist = (zn + ws[WS_WNORM + k]) - 2.0f * m;
    unsigned long long key =
        ((unsigned long long)__float_as_uint(dist) << 32) | (unsigned int)k;
#pragma unroll
    for (int s = 1; s < 64; s <<= 1) {
      const unsigned long long o = __shfl_xor((long long)key, s, 64);
      key = (o < key) ? o : key;
    }
    if ((threadIdx.x & 63) == 0) part[threadIdx.x >> 6] = key;
    __syncthreads();
    if (threadIdx.x == 0) {
      unsigned long long b = part[0];
      b = (part[1] < b) ? part[1] : b;
      b = (part[2] < b) ? part[2] : b;
      b = (part[3] < b) ? part[3] : b;
      atomicMin(&slots[row], b);
    }
    __syncthreads();
  }
}

__global__ void fallback_write(const float* __restrict__ ws, float* __restrict__ out) {
  const unsigned int i = blockIdx.x * blockDim.x + threadIdx.x;
  const unsigned int n = ((const unsigned int*)ws)[WS_OVF];
  if (i < n) {
    const int row = (int)((const unsigned int*)ws)[WS_OVFLIST + i];
    const unsigned long long key =
        ((const unsigned long long*)((const unsigned int*)ws + WS_SLOT))[row];
    out[IDX_OFF + row] = (float)(unsigned int)(key & 0xffffffffull);
  }
}

// 64 rows/block: gather W[idx], quantized_st = z + (q - z), loss partial sums.
__global__ void gather_loss_kernel(const float* __restrict__ z, const float* __restrict__ W,
                                   float* __restrict__ out, float* __restrict__ ws) {
  const int tid = threadIdx.x;
  const int rowBase = blockIdx.x * 64;
  float lsum = 0.0f;
  for (int p = 0; p < 16; ++p) {
    const int row = rowBase + p * 4 + (tid >> 6);
    const int c4 = tid & 63;
    const int idx = (int)out[IDX_OFF + row];
    const float4 zv = *(const float4*)(z + (size_t)row * DIM + c4 * 4);
    const float4 qv = *(const float4*)(W + (size_t)idx * DIM + c4 * 4);
    float4 t, o;
    t.x = qv.x - zv.x; t.y = qv.y - zv.y; t.z = qv.z - zv.z; t.w = qv.w - zv.w;
    o.x = zv.x + t.x;  o.y = zv.y + t.y;  o.z = zv.z + t.z;  o.w = zv.w + t.w;
    *(float4*)(out + (size_t)row * DIM + c4 * 4) = o;
    lsum += t.x * t.x + t.y * t.y + t.z * t.z + t.w * t.w;
  }
#pragma unroll
  for (int m = 1; m < 64; m <<= 1) lsum += __shfl_xor(lsum, m, 64);
  __shared__ float part[4];
  if ((tid & 63) == 0) part[tid >> 6] = lsum;
  __syncthreads();
  if (tid == 0) atomicAdd(&ws[WS_LOSS], (part[0] + part[1]) + (part[2] + part[3]));
}

__global__ void finalize_kernel(const float* __restrict__ ws, float* __restrict__ out) {
  if (threadIdx.x == 0 && blockIdx.x == 0) {
    const float mean = ws[WS_LOSS] / (float)(N_ROWS * DIM);
    out[LOSS_OFF] = mean + 0.25f * mean;
  }
}

extern "C" void kernel_launch(void* const* d_in, const int* in_sizes, int n_in,
                              void* d_out, int out_size, void* d_ws, size_t ws_size,
                              hipStream_t stream) {
  (void)in_sizes; (void)n_in; (void)out_size; (void)ws_size;
  const float* z = (const float*)d_in[0];
  const float* W = (const float*)d_in[1];
  float* out = (float*)d_out;
  float* ws = (float*)d_ws;
  unsigned short* outu = (unsigned short*)d_out;
  const unsigned short* wbf = outu + OUT_WBF_U16;
  const unsigned short* zbf = outu + OUT_ZBF_U16;
  uint2* candp = (uint2*)((float*)d_out + OUT_CAND_F);

  hipLaunchKernelGGL(precvt_kernel, dim3(18432), dim3(256), 0, stream, z, W, outu);
  hipLaunchKernelGGL(norms_kernel, dim3((N_ROWS + K_CODES) / 16), dim3(256), 0, stream,
                     z, W, ws);
  hipLaunchKernelGGL(gemm_screen_kernel, dim3(K_CODES / 128, N_ROWS / 128), dim3(256),
                     0, stream, zbf, wbf, ws, candp);
  hipLaunchKernelGGL(recheck_kernel, dim3(N_ROWS / 256), dim3(256), 0, stream,
                     z, W, ws, candp, out);
  hipLaunchKernelGGL(fallback_compute, dim3(2048), dim3(256), 0, stream, z, W, ws);
  hipLaunchKernelGGL(fallback_write, dim3(256), dim3(256), 0, stream, ws, out);
  hipLaunchKernelGGL(gather_loss_kernel, dim3(N_ROWS / 64), dim3(256), 0, stream,
                     z, W, out, ws);
  hipLaunchKernelGGL(finalize_kernel, dim3(1), dim3(64), 0, stream, ws, out);
}